// Round 1
// baseline (122.158 us; speedup 1.0000x reference)
//
#include <hip/hip_runtime.h>

// PrRoIPool2D(7,7, spatial_scale=0.5) exact integral form.
// features: [N=8, C=256, H=56, W=56] fp32
// rois:     [R=256, 5] fp32 (b, x1, y1, x2, y2) in image coords
// out:      [R, C, 7, 7] fp32
//
// out[r,c,p,q] = (1/area) * sum_h sum_w Iy[p,h] * F[b,c,h,w] * Ix[q,w]
// where Ix/Iy are 1D tent-basis integrals with support width bin+2 (<=6 taps).
// One thread per output element; taps computed in closed form per thread.

#define POOLED 7
__device__ __forceinline__ float Gfun(float t) {
    // antiderivative of tent max(0,1-|x|), with G(-1)=0; t pre-clipped to [-1,1]
    return (t <= 0.f) ? 0.5f * (t + 1.f) * (t + 1.f)
                      : 1.f - 0.5f * (1.f - t) * (1.f - t);
}
__device__ __forceinline__ float tent_int(float s, float e, float i) {
    float a = fminf(fmaxf(s - i, -1.f), 1.f);
    float b = fminf(fmaxf(e - i, -1.f), 1.f);
    return Gfun(b) - Gfun(a);
}

__global__ void prroi_kernel(const float* __restrict__ F,
                             const float* __restrict__ rois,
                             float* __restrict__ out,
                             int R, int C, int H, int W) {
    int idx = blockIdx.x * blockDim.x + threadIdx.x;
    int total = R * C * POOLED * POOLED;
    if (idx >= total) return;

    int q = idx % POOLED;
    int t = idx / POOLED;
    int p = t % POOLED;
    t /= POOLED;
    int c = t % C;
    int r = t / C;

    const float* roi = rois + (size_t)r * 5;
    int   b  = (int)roi[0];
    float x1 = roi[1] * 0.5f, y1 = roi[2] * 0.5f;
    float x2 = roi[3] * 0.5f, y2 = roi[4] * 0.5f;
    float bw = (x2 - x1) / (float)POOLED;
    float bh = (y2 - y1) / (float)POOLED;

    float xs = x1 + q * bw, xe = xs + bw;
    float ys = y1 + p * bh, ye = ys + bh;

    // support of the 1D integrals: grid points i with (i-1, i+1) ∩ (s, e) != {}
    int w0 = (int)ceilf(xs - 1.f); if (w0 < 0) w0 = 0;
    int w1 = (int)floorf(xe + 1.f); if (w1 > W - 1) w1 = W - 1;
    int h0 = (int)ceilf(ys - 1.f); if (h0 < 0) h0 = 0;
    int h1 = (int)floorf(ye + 1.f); if (h1 > H - 1) h1 = H - 1;

    // per-thread x taps (<=6 for this problem's bin sizes; 8 for safety)
    float wx[8];
    int nw = 0;
    for (int w = w0; w <= w1 && nw < 8; ++w) wx[nw++] = tent_int(xs, xe, (float)w);

    const float* Fp = F + (((size_t)b * C + c) * H) * W;
    float acc = 0.f;
    for (int h = h0; h <= h1; ++h) {
        float wy = tent_int(ys, ye, (float)h);
        const float* row = Fp + h * W + w0;
        float s = 0.f;
        #pragma unroll 8
        for (int k = 0; k < nw; ++k) s += wx[k] * row[k];
        acc += wy * s;
    }

    float area = bw * bh;
    out[idx] = (area > 0.f) ? acc / fmaxf(area, 1e-12f) : 0.f;
}

extern "C" void kernel_launch(void* const* d_in, const int* in_sizes, int n_in,
                              void* d_out, int out_size, void* d_ws, size_t ws_size,
                              hipStream_t stream) {
    const float* F    = (const float*)d_in[0];
    const float* rois = (const float*)d_in[1];
    float* out = (float*)d_out;

    const int C = 256, H = 56, W = 56;
    int R = in_sizes[1] / 5;
    int total = R * C * POOLED * POOLED;
    int block = 256;
    int grid = (total + block - 1) / block;
    prroi_kernel<<<grid, block, 0, stream>>>(F, rois, out, R, C, H, W);
}

// Round 2
// 82.529 us; speedup vs baseline: 1.4802x; 1.4802x over previous
//
#include <hip/hip_runtime.h>

// PrRoIPool2D(7,7, spatial_scale=0.5), exact integral form, separable.
// features: [N=8, C=256, H=56, W=56] fp32;  rois: [R,5];  out: [R, C, 7, 7]
//
// Block = (roi r, 32-channel chunk), 256 threads = 4 waves.
// Each wave streams 8 channels:
//   pass1: xint[hh][q] = sum_k wx[q][k] * F[h0a+hh][ox[q]+k]   (56 lanes: 8 rows x 7 bins)
//   pass2: out[p][q]   = inv_area * sum_ky wy[p][ky] * xint[yo_p+ky][q]  (49 lanes)
// Tent-integral weights computed once per wave into LDS (max 5 taps/bin;
// x padded to 8 taps at even offset for 8B-aligned float2 loads, extras are
// exactly 0 by construction of tent_int's clipping).

#define POOLED 7
#define CPER 32          // channels per block
#define CHUNKS 8         // C / CPER
#define NHMAX 24         // max window rows: ceil(6*bh)+6 <= 24 for this problem
#define XS 9             // xint row stride (floats), odd to spread banks

__device__ __forceinline__ float Gfun(float t) {
    return (t <= 0.f) ? 0.5f * (t + 1.f) * (t + 1.f)
                      : 1.f - 0.5f * (1.f - t) * (1.f - t);
}
__device__ __forceinline__ float tent_int(float s, float e, float i) {
    float a = fminf(fmaxf(s - i, -1.f), 1.f);
    float b = fminf(fmaxf(e - i, -1.f), 1.f);
    return Gfun(b) - Gfun(a);
}

__global__ __launch_bounds__(256, 8)
void prroi_kernel(const float* __restrict__ F, const float* __restrict__ rois,
                  float* __restrict__ out, int R, int C, int H, int W) {
    const int blk   = blockIdx.x;
    const int r     = blk >> 3;       // CHUNKS == 8
    const int chunk = blk & (CHUNKS - 1);
    const int wave  = threadIdx.x >> 6;
    const int lane  = threadIdx.x & 63;

    __shared__ float s_wx[4][7][8];
    __shared__ float s_wy[4][7][6];
    __shared__ int   s_ox[4][8];
    __shared__ int   s_oy[4][8];
    __shared__ float s_xint[4][NHMAX][XS];

    const float* roi = rois + (size_t)r * 5;
    const int   b  = (int)roi[0];
    const float x1 = roi[1] * 0.5f, y1 = roi[2] * 0.5f;
    const float x2 = roi[3] * 0.5f, y2 = roi[4] * 0.5f;
    const float bw = (x2 - x1) * (1.f / POOLED);
    const float bh = (y2 - y1) * (1.f / POOLED);
    const float area = bw * bh;
    const float inv_area = (area > 0.f) ? 1.f / fmaxf(area, 1e-12f) : 0.f;

    // ---- per-wave weight setup (redundant across waves; barrier-free channel loop)
    if (lane < 7) {                 // x bin q = lane
        float s = x1 + lane * bw, e = s + bw;
        int o = ((int)ceilf(s - 1.f)) & ~1;      // even offset -> 8B-aligned rows
        o = min(max(o, 0), W - 8);
        s_ox[wave][lane] = o;
        #pragma unroll
        for (int k = 0; k < 8; ++k) s_wx[wave][lane][k] = tent_int(s, e, (float)(o + k));
    } else if (lane < 14) {         // y bin p = lane-7
        int p = lane - 7;
        float s = y1 + p * bh, e = s + bh;
        int o = (int)ceilf(s - 1.f);
        o = min(max(o, 0), H - 6);
        s_oy[wave][p] = o;
        #pragma unroll
        for (int k = 0; k < 6; ++k) s_wy[wave][p][k] = tent_int(s, e, (float)(o + k));
    }
    __syncthreads();   // once per block; covers the (wave-redundant) weight writes

    // ---- hoist per-lane state
    // pass1 role: q1 = lane&7 (active q1<7), hs = lane>>3 (row sub-index 0..7)
    const int q1 = lane & 7, hs = lane >> 3;
    const bool a1 = (q1 < 7);
    const int qq = a1 ? q1 : 0;
    const int ox1 = s_ox[wave][qq];
    float wx1[8];
    #pragma unroll
    for (int k = 0; k < 8; ++k) wx1[k] = s_wx[wave][qq][k];

    // pass2 role: p2 = lane>>3, q2 = lane&7, active lanes: lane<56 && q2<7
    const int p2 = lane >> 3, q2 = lane & 7;
    const bool a2 = (lane < 56) && (q2 < 7);
    const int pp = (p2 < 7) ? p2 : 0;
    const int h0a = s_oy[wave][0];
    const int nh  = s_oy[wave][6] + 6 - h0a;      // <= NHMAX
    const int yo2 = s_oy[wave][pp] - h0a;
    float wy2[6];
    #pragma unroll
    for (int k = 0; k < 6; ++k) wy2[k] = s_wy[wave][pp][k];

    // ---- stream channels: wave `wave` handles CPER/4 = 8 channels
    const int c0 = chunk * CPER + wave * (CPER / 4);
    const float* Fb = F + ((size_t)b * C) * H * W;

    for (int i = 0; i < CPER / 4; ++i) {
        const int c = c0 + i;
        const float* Fc = Fb + (size_t)c * H * W;

        // pass1: 3 iterations cover rows 0..23
        #pragma unroll
        for (int it = 0; it < 3; ++it) {
            int hh = it * 8 + hs;
            if (a1 && hh < nh) {
                const float2* rp = (const float2*)(Fc + (h0a + hh) * W + ox1);
                float2 v0 = rp[0], v1 = rp[1], v2 = rp[2], v3 = rp[3];
                float sacc = wx1[0] * v0.x + wx1[1] * v0.y
                           + wx1[2] * v1.x + wx1[3] * v1.y
                           + wx1[4] * v2.x + wx1[5] * v2.y
                           + wx1[6] * v3.x + wx1[7] * v3.y;
                s_xint[wave][hh][q1] = sacc;
            }
        }
        // pass2 (same wave; LDS ordering handled by compiler-inserted waits)
        if (a2) {
            float acc = 0.f;
            #pragma unroll
            for (int ky = 0; ky < 6; ++ky)
                acc += wy2[ky] * s_xint[wave][yo2 + ky][q2];
            out[((size_t)r * C + c) * 49 + p2 * 7 + q2] = acc * inv_area;
        }
    }
}

extern "C" void kernel_launch(void* const* d_in, const int* in_sizes, int n_in,
                              void* d_out, int out_size, void* d_ws, size_t ws_size,
                              hipStream_t stream) {
    const float* F    = (const float*)d_in[0];
    const float* rois = (const float*)d_in[1];
    float* out = (float*)d_out;

    const int C = 256, H = 56, W = 56;
    int R = in_sizes[1] / 5;
    dim3 grid(R * CHUNKS), block(256);
    prroi_kernel<<<grid, block, 0, stream>>>(F, rois, out, R, C, H, W);
}